// Round 3
// baseline (465.455 us; speedup 1.0000x reference)
//
#include <hip/hip_runtime.h>
#include <stdint.h>

#define NEUR 1024
#define BM 64
#define THREADS 1024

typedef short  s16x8  __attribute__((ext_vector_type(8)));
typedef __bf16 bf16x8 __attribute__((ext_vector_type(8)));
typedef float  f32x16 __attribute__((ext_vector_type(16)));

__device__ __forceinline__ unsigned short f2bf(float f){
  unsigned u = __builtin_bit_cast(unsigned, f);
  u += 0x7FFFu + ((u >> 16) & 1u);          // round-to-nearest-even
  return (unsigned short)(u >> 16);
}
__device__ __forceinline__ float bf2f(unsigned short h){
  unsigned u = ((unsigned)h) << 16;
  return __builtin_bit_cast(float, u);
}
__device__ __forceinline__ f32x16 mfma32(bf16x8 a, bf16x8 b, f32x16 c){
  return __builtin_amdgcn_mfma_f32_32x32x16_bf16(a, b, c, 0, 0, 0);
}
__device__ __forceinline__ f32x16 zero16(){
  f32x16 v;
#pragma unroll
  for (int r = 0; r < 16; ++r) v[r] = 0.f;
  return v;
}

// Pre-swizzle weights into MFMA-fragment order so GEMM loads are coalesced.
// w2opt[((nt*64 + ks)*64 + l)*8 + j] = bf16(W2[nt*32 + (l&31)][ks*16 + (l>>5)*8 + j])
// w1opt[((nt*2  + ks)*64 + l)*8 + j] = bf16(W1 padded to K=32, same fragment map)
__global__ void prep_kernel(const float* __restrict__ W1, const float* __restrict__ W2,
                            unsigned short* __restrict__ w2opt, unsigned short* __restrict__ w1opt){
  const int nchunks = NEUR * 128;            // 8-float chunks of W2 (read-coalesced)
  const int total = nchunks + 4096;          // + w1opt lane-blocks
  for (int i = blockIdx.x*blockDim.x + threadIdx.x; i < total; i += gridDim.x*blockDim.x){
    if (i < nchunks){
      const int col = i >> 7, c8 = i & 127;
      const float* src = W2 + (size_t)col*NEUR + c8*8;
      const int ks = c8 >> 1, lh = c8 & 1, l = lh*32 + (col & 31), nt = col >> 5;
      unsigned short* dst = w2opt + (((size_t)(nt*64 + ks)*64 + l) * 8);
#pragma unroll
      for (int j = 0; j < 8; ++j) dst[j] = f2bf(src[j]);
    } else {
      const int o = i - nchunks;             // ((nt*2+ks)*64 + l)
      const int nt = o >> 7, ks = (o >> 6) & 1, l = o & 63;
      const int col = nt*32 + (l & 31);
      unsigned short* dst = w1opt + (size_t)o * 8;
#pragma unroll
      for (int j = 0; j < 8; ++j){
        const int k = ks*16 + (l >> 5)*8 + j;
        dst[j] = (k < 10) ? f2bf(W1[col*10 + k]) : (unsigned short)0;
      }
    }
  }
}

template<bool BFWS>
__global__ __launch_bounds__(THREADS, 4) void mlp_kernel(
    const float* __restrict__ x,
    const float* __restrict__ Wx, const float* __restrict__ bxp,
    const float* __restrict__ Wu, const float* __restrict__ bup,
    const float* __restrict__ W1, const float* __restrict__ b1,
    const float* __restrict__ W2f, const float* __restrict__ b2,
    const float* __restrict__ W3, const float* __restrict__ b3,
    const unsigned short* __restrict__ w2opt, const unsigned short* __restrict__ w1opt,
    float* __restrict__ out)
{
  extern __shared__ char smem[];
  unsigned short* l1p = (unsigned short*)smem;   // [64][40] bf16 (5120 B, padded stride)
  char* h1            = smem + 5120;             // 64 rows x 2048 B, XOR-swizzled bf16

  const int tid = threadIdx.x;
  const int l   = tid & 63;
  const int wid = tid >> 6;                      // 16 waves
  const int l31 = l & 31;
  const int lh  = l >> 5;
  const long rbase = (long)blockIdx.x * BM;

  // ---- 1. stage x tile (64*25 f32), overlaying h1 region
  float* xs = (float*)h1;
  for (int i = tid; i < BM*25; i += THREADS) xs[i] = x[rbase*25 + i];
  __syncthreads();

  // ---- 2. l1 features (f32 exact), bf16-pad to K=32 in l1p
  if (tid < BM){
    const float* xr = xs + tid*25;
    float l1v[10];
#pragma unroll
    for (int g = 0; g < 3; ++g)
#pragma unroll
      for (int o = 0; o < 2; ++o){
        float s = bxp[o];
#pragma unroll
        for (int i = 0; i < 5; ++i) s += xr[g + 3*i] * Wx[o*5 + i];
        l1v[g*2 + o] = fmaxf(s, 0.f);
      }
#pragma unroll
    for (int g = 0; g < 2; ++g)
#pragma unroll
      for (int o = 0; o < 2; ++o){
        float s = bup[o];
#pragma unroll
        for (int i = 0; i < 5; ++i) s += xr[15 + g + 2*i] * Wu[o*5 + i];
        l1v[6 + g*2 + o] = fmaxf(s, 0.f);
      }
    unsigned short* dst = l1p + tid*40;
#pragma unroll
    for (int i = 0; i < 10; ++i) dst[i] = f2bf(l1v[i]);
#pragma unroll
    for (int i = 10; i < 32; ++i) dst[i] = 0;
  }
  __syncthreads();

  const int swz   = (l31 & 7) << 4;              // row-dependent LDS XOR swizzle
  const int aoff0 = l31*2048;                    // A row bases (bytes into h1)
  const int aoff1 = aoff0 + 32*2048;

// LDS A fragment loads (rows l31 / 32+l31, 16B each, swizzled)
#define LOADA(A0_, A1_, KS) do{                                                   \
    const int cb_ = (((KS)*32) + lh*16) ^ swz;                                    \
    A0_ = __builtin_bit_cast(bf16x8, *reinterpret_cast<const s16x8*>(h1 + aoff0 + cb_)); \
    A1_ = __builtin_bit_cast(bf16x8, *reinterpret_cast<const s16x8*>(h1 + aoff1 + cb_)); \
  }while(0)

  // store helper: h2/h1 tile write (relu(acc+bias) -> swizzled bf16 LDS)
#define STORE_H(ACC_, MT_, NT_, BIAS_) do{                                        \
    const int col_ = wid*64 + (NT_)*32 + l31;                                     \
    const float bv_ = BIAS_[col_];                                                \
    _Pragma("unroll")                                                             \
    for (int r = 0; r < 16; ++r){                                                 \
      const int row_ = (MT_)*32 + (r & 3) + 8*(r >> 2) + 4*lh;                    \
      const float v_ = fmaxf(ACC_[r] + bv_, 0.f);                                 \
      *reinterpret_cast<unsigned short*>(h1 + row_*2048 + ((col_*2) ^ ((row_ & 7) << 4))) = f2bf(v_); \
    }                                                                             \
  }while(0)

  // ---- 3. GEMM1: h1[64][wid*64 .. +64) = relu(l1 @ W1^T + b1)
  {
    f32x16 c00 = zero16(), c01 = zero16(), c10 = zero16(), c11 = zero16();
#pragma unroll
    for (int ks = 0; ks < 2; ++ks){
      bf16x8 a0, a1, b0, b1;
      a0 = __builtin_bit_cast(bf16x8, *reinterpret_cast<const s16x8*>(smem + (l31)*80 + ks*32 + lh*16));
      a1 = __builtin_bit_cast(bf16x8, *reinterpret_cast<const s16x8*>(smem + (32 + l31)*80 + ks*32 + lh*16));
      if constexpr (BFWS){
        b0 = __builtin_bit_cast(bf16x8, *reinterpret_cast<const s16x8*>(
            w1opt + (((size_t)((wid*2 + 0)*2 + ks)*64 + l) * 8)));
        b1 = __builtin_bit_cast(bf16x8, *reinterpret_cast<const s16x8*>(
            w1opt + (((size_t)((wid*2 + 1)*2 + ks)*64 + l) * 8)));
      } else {
        s16x8 r0, r1;
        const int c0 = wid*64 + l31, c1 = c0 + 32;
#pragma unroll
        for (int j = 0; j < 8; ++j){
          const int k = ks*16 + lh*8 + j;
          r0[j] = (k < 10) ? (short)f2bf(W1[c0*10 + k]) : (short)0;
          r1[j] = (k < 10) ? (short)f2bf(W1[c1*10 + k]) : (short)0;
        }
        b0 = __builtin_bit_cast(bf16x8, r0);
        b1 = __builtin_bit_cast(bf16x8, r1);
      }
      c00 = mfma32(a0, b0, c00);
      c10 = mfma32(a1, b0, c10);
      c01 = mfma32(a0, b1, c01);
      c11 = mfma32(a1, b1, c11);
    }
    STORE_H(c00, 0, 0, b1);
    STORE_H(c10, 1, 0, b1);
    STORE_H(c01, 0, 1, b1);
    STORE_H(c11, 1, 1, b1);
  }
  __syncthreads();

  // ---- 4. GEMM2: per wave 64 rows x 64 cols, K=1024; B 1-deep pipelined, A single-buffered
  f32x16 acc00 = zero16(), acc01 = zero16(), acc10 = zero16(), acc11 = zero16();

  const unsigned short* pB0 = w2opt + ((size_t)(wid*2 + 0)*4096 + l) * 8;
  const unsigned short* pB1 = pB0 + (size_t)4096*8;

#define LOADB(B0_, B1_, KS) do{                                                   \
    if constexpr (BFWS){                                                          \
      B0_ = __builtin_bit_cast(bf16x8, *reinterpret_cast<const s16x8*>(pB0 + (KS)*512)); \
      B1_ = __builtin_bit_cast(bf16x8, *reinterpret_cast<const s16x8*>(pB1 + (KS)*512)); \
    } else {                                                                      \
      const int c0_ = wid*64 + l31, c1_ = c0_ + 32;                               \
      const float* p0_ = W2f + (size_t)c0_*NEUR + (KS)*16 + lh*8;                 \
      const float* p1_ = W2f + (size_t)c1_*NEUR + (KS)*16 + lh*8;                 \
      s16x8 r0_, r1_;                                                             \
      _Pragma("unroll")                                                           \
      for (int j = 0; j < 8; ++j){ r0_[j] = (short)f2bf(p0_[j]); r1_[j] = (short)f2bf(p1_[j]); } \
      B0_ = __builtin_bit_cast(bf16x8, r0_);                                      \
      B1_ = __builtin_bit_cast(bf16x8, r1_);                                      \
    }                                                                             \
  }while(0)

  {
    bf16x8 A0, A1, B0c, B1c, B0n, B1n;
    LOADB(B0c, B1c, 0);
    for (int ks = 0; ks < 64; ks += 2){
      LOADB(B0n, B1n, ks + 1);
      LOADA(A0, A1, ks);
      acc00 = mfma32(A0, B0c, acc00);
      acc10 = mfma32(A1, B0c, acc10);
      acc01 = mfma32(A0, B1c, acc01);
      acc11 = mfma32(A1, B1c, acc11);
      if (ks + 2 < 64) LOADB(B0c, B1c, ks + 2);
      LOADA(A0, A1, ks + 1);
      acc00 = mfma32(A0, B0n, acc00);
      acc10 = mfma32(A1, B0n, acc10);
      acc01 = mfma32(A0, B1n, acc01);
      acc11 = mfma32(A1, B1n, acc11);
    }
  }
  __syncthreads();   // everyone done reading h1

  // ---- 5. h2 = relu(acc + b2) -> back into h1 (bf16, swizzled)
  STORE_H(acc00, 0, 0, b2);
  STORE_H(acc10, 1, 0, b2);
  STORE_H(acc01, 0, 1, b2);
  STORE_H(acc11, 1, 1, b2);
  __syncthreads();

  // ---- 6. GEMM3 (f32 VALU): wave wid owns rows wid*4 .. wid*4+3
  float s00=0.f,s01=0.f,s02=0.f, s10=0.f,s11=0.f,s12=0.f;
  float s20=0.f,s21=0.f,s22=0.f, s30=0.f,s31=0.f,s32=0.f;
#pragma unroll
  for (int h = 0; h < 2; ++h){
    const int k0 = h*512 + l*8;
    float w3v[3][8];
#pragma unroll
    for (int j = 0; j < 3; ++j)
#pragma unroll
      for (int i = 0; i < 8; ++i) w3v[j][i] = W3[j*NEUR + k0 + i];
#pragma unroll
    for (int rr = 0; rr < 4; ++rr){
      const int row = wid*4 + rr;
      s16x8 raw = *reinterpret_cast<const s16x8*>(
          h1 + row*2048 + ((h*1024 + l*16) ^ ((row & 7) << 4)));
      float a0=0.f, a1=0.f, a2=0.f;
#pragma unroll
      for (int i = 0; i < 8; ++i){
        const float hv = bf2f((unsigned short)raw[i]);
        a0 += hv * w3v[0][i];
        a1 += hv * w3v[1][i];
        a2 += hv * w3v[2][i];
      }
      if (rr == 0){ s00 += a0; s01 += a1; s02 += a2; }
      else if (rr == 1){ s10 += a0; s11 += a1; s12 += a2; }
      else if (rr == 2){ s20 += a0; s21 += a1; s22 += a2; }
      else { s30 += a0; s31 += a1; s32 += a2; }
    }
  }
#pragma unroll
  for (int off = 1; off < 64; off <<= 1){
    s00 += __shfl_xor(s00, off, 64); s01 += __shfl_xor(s01, off, 64); s02 += __shfl_xor(s02, off, 64);
    s10 += __shfl_xor(s10, off, 64); s11 += __shfl_xor(s11, off, 64); s12 += __shfl_xor(s12, off, 64);
    s20 += __shfl_xor(s20, off, 64); s21 += __shfl_xor(s21, off, 64); s22 += __shfl_xor(s22, off, 64);
    s30 += __shfl_xor(s30, off, 64); s31 += __shfl_xor(s31, off, 64); s32 += __shfl_xor(s32, off, 64);
  }
  if (l == 0){
    const int row = wid*4;
    out[(rbase + row + 0)*3 + 0] = 1.f / (1.f + __expf(-(s00 + b3[0])));
    out[(rbase + row + 0)*3 + 1] = 1.f / (1.f + __expf(-(s01 + b3[1])));
    out[(rbase + row + 0)*3 + 2] = 1.f / (1.f + __expf(-(s02 + b3[2])));
    out[(rbase + row + 1)*3 + 0] = 1.f / (1.f + __expf(-(s10 + b3[0])));
    out[(rbase + row + 1)*3 + 1] = 1.f / (1.f + __expf(-(s11 + b3[1])));
    out[(rbase + row + 1)*3 + 2] = 1.f / (1.f + __expf(-(s12 + b3[2])));
    out[(rbase + row + 2)*3 + 0] = 1.f / (1.f + __expf(-(s20 + b3[0])));
    out[(rbase + row + 2)*3 + 1] = 1.f / (1.f + __expf(-(s21 + b3[1])));
    out[(rbase + row + 2)*3 + 2] = 1.f / (1.f + __expf(-(s22 + b3[2])));
    out[(rbase + row + 3)*3 + 0] = 1.f / (1.f + __expf(-(s30 + b3[0])));
    out[(rbase + row + 3)*3 + 1] = 1.f / (1.f + __expf(-(s31 + b3[1])));
    out[(rbase + row + 3)*3 + 2] = 1.f / (1.f + __expf(-(s32 + b3[2])));
  }
#undef LOADA
#undef LOADB
#undef STORE_H
}

extern "C" void kernel_launch(void* const* d_in, const int* in_sizes, int n_in,
                              void* d_out, int out_size, void* d_ws, size_t ws_size,
                              hipStream_t stream){
  const float* x  = (const float*)d_in[0];
  const float* Wx = (const float*)d_in[1];
  const float* bx = (const float*)d_in[2];
  const float* Wu = (const float*)d_in[3];
  const float* bu = (const float*)d_in[4];
  const float* W1 = (const float*)d_in[5];
  const float* b1 = (const float*)d_in[6];
  const float* W2 = (const float*)d_in[7];
  const float* b2 = (const float*)d_in[8];
  const float* W3 = (const float*)d_in[9];
  const float* b3 = (const float*)d_in[10];
  float* out = (float*)d_out;

  const int batch   = in_sizes[0] / 25;
  const int nblocks = batch / BM;
  const size_t ws_need = (size_t)(32*64*64*8 + 4096*8) * sizeof(unsigned short); // ~2.1 MB
  const int smem = 5120 + BM*2048;   // 136192 B

  if (ws_size >= ws_need){
    unsigned short* w2opt = (unsigned short*)d_ws;
    unsigned short* w1opt = w2opt + (size_t)32*64*64*8;
    prep_kernel<<<512, 256, 0, stream>>>(W1, W2, w2opt, w1opt);
    hipFuncSetAttribute(reinterpret_cast<const void*>(mlp_kernel<true>),
                        hipFuncAttributeMaxDynamicSharedMemorySize, smem);
    mlp_kernel<true><<<nblocks, THREADS, smem, stream>>>(
        x, Wx, bx, Wu, bu, W1, b1, W2, b2, W3, b3, w2opt, w1opt, out);
  } else {
    hipFuncSetAttribute(reinterpret_cast<const void*>(mlp_kernel<false>),
                        hipFuncAttributeMaxDynamicSharedMemorySize, smem);
    mlp_kernel<false><<<nblocks, THREADS, smem, stream>>>(
        x, Wx, bx, Wu, bu, W1, b1, W2, b2, W3, b3, nullptr, nullptr, out);
  }
}

// Round 4
// 351.854 us; speedup vs baseline: 1.3229x; 1.3229x over previous
//
#include <hip/hip_runtime.h>
#include <stdint.h>

#define NEUR 1024
#define BM 64
#define THREADS 512
#define H1S 2064   // h1 row stride in bytes (1024*2 + 16 pad -> bank spread, imm-foldable)

typedef short  s16x8  __attribute__((ext_vector_type(8)));
typedef __bf16 bf16x8 __attribute__((ext_vector_type(8)));
typedef float  f32x16 __attribute__((ext_vector_type(16)));

__device__ __forceinline__ unsigned short f2bf(float f){
  unsigned u = __builtin_bit_cast(unsigned, f);
  u += 0x7FFFu + ((u >> 16) & 1u);          // round-to-nearest-even
  return (unsigned short)(u >> 16);
}
__device__ __forceinline__ float bf2f(unsigned short h){
  unsigned u = ((unsigned)h) << 16;
  return __builtin_bit_cast(float, u);
}
__device__ __forceinline__ f32x16 mfma32(bf16x8 a, bf16x8 b, f32x16 c){
  return __builtin_amdgcn_mfma_f32_32x32x16_bf16(a, b, c, 0, 0, 0);
}
__device__ __forceinline__ f32x16 zero16(){
  f32x16 v;
#pragma unroll
  for (int r = 0; r < 16; ++r) v[r] = 0.f;
  return v;
}

// Pre-swizzle weights into MFMA-fragment order so GEMM loads are coalesced.
// w2opt[((nt*64 + ks)*64 + l)*8 + j] = bf16(W2[nt*32 + (l&31)][ks*16 + (l>>5)*8 + j])
// w1opt[((nt*2  + ks)*64 + l)*8 + j] = bf16(W1 padded to K=32, same fragment map)
__global__ void prep_kernel(const float* __restrict__ W1, const float* __restrict__ W2,
                            unsigned short* __restrict__ w2opt, unsigned short* __restrict__ w1opt){
  const int nchunks = NEUR * 128;            // 8-float chunks of W2 (read-coalesced)
  const int total = nchunks + 4096;          // + w1opt lane-blocks
  for (int i = blockIdx.x*blockDim.x + threadIdx.x; i < total; i += gridDim.x*blockDim.x){
    if (i < nchunks){
      const int col = i >> 7, c8 = i & 127;
      const float* src = W2 + (size_t)col*NEUR + c8*8;
      const int ks = c8 >> 1, lf = c8 & 1, lane = lf*32 + (col & 31), nt = col >> 5;
      unsigned short* dst = w2opt + (((size_t)(nt*64 + ks)*64 + lane) * 8);
#pragma unroll
      for (int j = 0; j < 8; ++j) dst[j] = f2bf(src[j]);
    } else {
      const int o = i - nchunks;             // ((nt*2+ks)*64 + lane)
      const int nt = o >> 7, ks = (o >> 6) & 1, lane = o & 63;
      const int col = nt*32 + (lane & 31);
      unsigned short* dst = w1opt + (size_t)o * 8;
#pragma unroll
      for (int j = 0; j < 8; ++j){
        const int k = ks*16 + (lane >> 5)*8 + j;
        dst[j] = (k < 10) ? f2bf(W1[col*10 + k]) : (unsigned short)0;
      }
    }
  }
}

template<bool BFWS>
__global__ __launch_bounds__(THREADS, 2) void mlp_kernel(
    const float* __restrict__ x,
    const float* __restrict__ Wx, const float* __restrict__ bxp,
    const float* __restrict__ Wu, const float* __restrict__ bup,
    const float* __restrict__ W1, const float* __restrict__ b1,
    const float* __restrict__ W2f, const float* __restrict__ b2,
    const float* __restrict__ W3, const float* __restrict__ b3,
    const unsigned short* __restrict__ w2opt, const unsigned short* __restrict__ w1opt,
    float* __restrict__ out)
{
  extern __shared__ char smem[];
  unsigned short* l1p = (unsigned short*)smem;   // [64][40] bf16 (5120 B, padded stride)
  char* h1            = smem + 5120;             // 64 rows x 2064 B (padded), bf16

  const int tid = threadIdx.x;
  const int l   = tid & 63;
  const int wid = tid >> 6;                      // 8 waves
  const int l31 = l & 31;
  const int lh  = l >> 5;
  const long rbase = (long)blockIdx.x * BM;

  // ---- 1. stage x tile (64*25 f32), overlaying h1 region
  float* xs = (float*)h1;
  for (int i = tid; i < BM*25; i += THREADS) xs[i] = x[rbase*25 + i];
  __syncthreads();

  // ---- 2. l1 features (f32 exact), bf16-pad to K=32 in l1p
  if (tid < BM){
    const float* xr = xs + tid*25;
    float l1v[10];
#pragma unroll
    for (int g = 0; g < 3; ++g)
#pragma unroll
      for (int o = 0; o < 2; ++o){
        float s = bxp[o];
#pragma unroll
        for (int i = 0; i < 5; ++i) s += xr[g + 3*i] * Wx[o*5 + i];
        l1v[g*2 + o] = fmaxf(s, 0.f);
      }
#pragma unroll
    for (int g = 0; g < 2; ++g)
#pragma unroll
      for (int o = 0; o < 2; ++o){
        float s = bup[o];
#pragma unroll
        for (int i = 0; i < 5; ++i) s += xr[15 + g + 2*i] * Wu[o*5 + i];
        l1v[6 + g*2 + o] = fmaxf(s, 0.f);
      }
    unsigned short* dst = l1p + tid*40;
#pragma unroll
    for (int i = 0; i < 10; ++i) dst[i] = f2bf(l1v[i]);
#pragma unroll
    for (int i = 10; i < 32; ++i) dst[i] = 0;
  }
  __syncthreads();

  // ---- 3. GEMM1: h1[64][wid*128 .. +128) = relu(l1 @ W1^T + b1)
  {
    f32x16 c[2][4];
#pragma unroll
    for (int mt = 0; mt < 2; ++mt)
#pragma unroll
      for (int nt = 0; nt < 4; ++nt) c[mt][nt] = zero16();

#pragma unroll
    for (int ks = 0; ks < 2; ++ks){
      bf16x8 a0 = __builtin_bit_cast(bf16x8, *reinterpret_cast<const s16x8*>(
          smem + l31*80 + ks*32 + lh*16));
      bf16x8 a1 = __builtin_bit_cast(bf16x8, *reinterpret_cast<const s16x8*>(
          smem + (32 + l31)*80 + ks*32 + lh*16));
      bf16x8 b[4];
#pragma unroll
      for (int nt = 0; nt < 4; ++nt){
        if constexpr (BFWS){
          b[nt] = __builtin_bit_cast(bf16x8, *reinterpret_cast<const s16x8*>(
              w1opt + (((size_t)((wid*4 + nt)*2 + ks)*64 + l) * 8)));
        } else {
          const int col = wid*128 + nt*32 + l31;
          s16x8 raw;
#pragma unroll
          for (int j = 0; j < 8; ++j){
            const int k = ks*16 + lh*8 + j;
            raw[j] = (k < 10) ? (short)f2bf(W1[col*10 + k]) : (short)0;
          }
          b[nt] = __builtin_bit_cast(bf16x8, raw);
        }
      }
#pragma unroll
      for (int nt = 0; nt < 4; ++nt){
        c[0][nt] = mfma32(a0, b[nt], c[0][nt]);
        c[1][nt] = mfma32(a1, b[nt], c[1][nt]);
      }
    }
#pragma unroll
    for (int nt = 0; nt < 4; ++nt){
      const int col = wid*128 + nt*32 + l31;
      const float bv = b1[col];
#pragma unroll
      for (int mt = 0; mt < 2; ++mt)
#pragma unroll
        for (int r = 0; r < 16; ++r){
          const int row = mt*32 + (r & 3) + 8*(r >> 2) + 4*lh;
          *reinterpret_cast<unsigned short*>(h1 + row*H1S + col*2) =
              f2bf(fmaxf(c[mt][nt][r] + bv, 0.f));
        }
    }
  }
  __syncthreads();

  // ---- 4. GEMM2: per wave 64 rows x 128 cols, K=1024, A+B register double-buffer
  f32x16 acc[2][4];
#pragma unroll
  for (int mt = 0; mt < 2; ++mt)
#pragma unroll
    for (int nt = 0; nt < 4; ++nt) acc[mt][nt] = zero16();

  const unsigned short* pB0 = w2opt + ((size_t)(wid*4 + 0)*4096 + l) * 8;
  const unsigned short* pB1 = w2opt + ((size_t)(wid*4 + 1)*4096 + l) * 8;
  const unsigned short* pB2 = w2opt + ((size_t)(wid*4 + 2)*4096 + l) * 8;
  const unsigned short* pB3 = w2opt + ((size_t)(wid*4 + 3)*4096 + l) * 8;
  const int aA0 = l31*H1S + lh*16;
  const int aA1 = aA0 + 32*H1S;

#define LOADA2(A0_, A1_, KS) do{                                                   \
    A0_ = __builtin_bit_cast(bf16x8, *reinterpret_cast<const s16x8*>(h1 + aA0 + (KS)*32)); \
    A1_ = __builtin_bit_cast(bf16x8, *reinterpret_cast<const s16x8*>(h1 + aA1 + (KS)*32)); \
  }while(0)

#define LOADB4(B0_, B1_, B2_, B3_, KS) do{                                         \
    if constexpr (BFWS){                                                           \
      B0_ = __builtin_bit_cast(bf16x8, *reinterpret_cast<const s16x8*>(pB0 + (KS)*512)); \
      B1_ = __builtin_bit_cast(bf16x8, *reinterpret_cast<const s16x8*>(pB1 + (KS)*512)); \
      B2_ = __builtin_bit_cast(bf16x8, *reinterpret_cast<const s16x8*>(pB2 + (KS)*512)); \
      B3_ = __builtin_bit_cast(bf16x8, *reinterpret_cast<const s16x8*>(pB3 + (KS)*512)); \
    } else {                                                                       \
      s16x8 r_[4];                                                                 \
      _Pragma("unroll")                                                            \
      for (int nt_ = 0; nt_ < 4; ++nt_){                                           \
        const int col_ = wid*128 + nt_*32 + l31;                                   \
        const float* p_ = W2f + (size_t)col_*NEUR + (KS)*16 + lh*8;                \
        _Pragma("unroll")                                                          \
        for (int j_ = 0; j_ < 8; ++j_) r_[nt_][j_] = (short)f2bf(p_[j_]);          \
      }                                                                            \
      B0_ = __builtin_bit_cast(bf16x8, r_[0]);                                     \
      B1_ = __builtin_bit_cast(bf16x8, r_[1]);                                     \
      B2_ = __builtin_bit_cast(bf16x8, r_[2]);                                     \
      B3_ = __builtin_bit_cast(bf16x8, r_[3]);                                     \
    }                                                                              \
  }while(0)

  {
    bf16x8 Aa0, Aa1, Ab0, Ab1;
    bf16x8 Ba0, Ba1, Ba2, Ba3, Bb0, Bb1, Bb2, Bb3;
    LOADB4(Ba0, Ba1, Ba2, Ba3, 0);
    LOADA2(Aa0, Aa1, 0);
    for (int ks = 0; ks < 64; ks += 2){
      LOADB4(Bb0, Bb1, Bb2, Bb3, ks + 1);
      LOADA2(Ab0, Ab1, ks + 1);
      acc[0][0] = mfma32(Aa0, Ba0, acc[0][0]);
      acc[1][0] = mfma32(Aa1, Ba0, acc[1][0]);
      acc[0][1] = mfma32(Aa0, Ba1, acc[0][1]);
      acc[1][1] = mfma32(Aa1, Ba1, acc[1][1]);
      acc[0][2] = mfma32(Aa0, Ba2, acc[0][2]);
      acc[1][2] = mfma32(Aa1, Ba2, acc[1][2]);
      acc[0][3] = mfma32(Aa0, Ba3, acc[0][3]);
      acc[1][3] = mfma32(Aa1, Ba3, acc[1][3]);
      if (ks + 2 < 64){
        LOADB4(Ba0, Ba1, Ba2, Ba3, ks + 2);
        LOADA2(Aa0, Aa1, ks + 2);
      }
      acc[0][0] = mfma32(Ab0, Bb0, acc[0][0]);
      acc[1][0] = mfma32(Ab1, Bb0, acc[1][0]);
      acc[0][1] = mfma32(Ab0, Bb1, acc[0][1]);
      acc[1][1] = mfma32(Ab1, Bb1, acc[1][1]);
      acc[0][2] = mfma32(Ab0, Bb2, acc[0][2]);
      acc[1][2] = mfma32(Ab1, Bb2, acc[1][2]);
      acc[0][3] = mfma32(Ab0, Bb3, acc[0][3]);
      acc[1][3] = mfma32(Ab1, Bb3, acc[1][3]);
    }
  }
  __syncthreads();   // everyone done reading h1

  // ---- 5. h2 = relu(acc + b2) -> back into h1 (bf16, padded layout)
#pragma unroll
  for (int nt = 0; nt < 4; ++nt){
    const int col = wid*128 + nt*32 + l31;
    const float bv = b2[col];
#pragma unroll
    for (int mt = 0; mt < 2; ++mt)
#pragma unroll
      for (int r = 0; r < 16; ++r){
        const int row = mt*32 + (r & 3) + 8*(r >> 2) + 4*lh;
        *reinterpret_cast<unsigned short*>(h1 + row*H1S + col*2) =
            f2bf(fmaxf(acc[mt][nt][r] + bv, 0.f));
      }
  }
  __syncthreads();

  // ---- 6. GEMM3 (f32 VALU): wave wid owns rows wid*8 .. wid*8+7
  float s[8][3];
#pragma unroll
  for (int rr = 0; rr < 8; ++rr)
#pragma unroll
    for (int j = 0; j < 3; ++j) s[rr][j] = 0.f;

#pragma unroll
  for (int h = 0; h < 2; ++h){
    const int k0 = h*512 + l*8;
    float w3v[3][8];
#pragma unroll
    for (int j = 0; j < 3; ++j)
#pragma unroll
      for (int i = 0; i < 8; ++i) w3v[j][i] = W3[j*NEUR + k0 + i];
#pragma unroll
    for (int rr = 0; rr < 8; ++rr){
      const int row = wid*8 + rr;
      s16x8 raw = *reinterpret_cast<const s16x8*>(h1 + row*H1S + k0*2);
#pragma unroll
      for (int i = 0; i < 8; ++i){
        const float hv = bf2f((unsigned short)raw[i]);
        s[rr][0] += hv * w3v[0][i];
        s[rr][1] += hv * w3v[1][i];
        s[rr][2] += hv * w3v[2][i];
      }
    }
  }
#pragma unroll
  for (int off = 1; off < 64; off <<= 1)
#pragma unroll
    for (int rr = 0; rr < 8; ++rr)
#pragma unroll
      for (int j = 0; j < 3; ++j) s[rr][j] += __shfl_xor(s[rr][j], off, 64);

  if (l == 0){
#pragma unroll
    for (int rr = 0; rr < 8; ++rr){
      const int row = wid*8 + rr;
#pragma unroll
      for (int j = 0; j < 3; ++j)
        out[(rbase + row)*3 + j] = 1.f / (1.f + __expf(-(s[rr][j] + b3[j])));
    }
  }
#undef LOADA2
#undef LOADB4
}

extern "C" void kernel_launch(void* const* d_in, const int* in_sizes, int n_in,
                              void* d_out, int out_size, void* d_ws, size_t ws_size,
                              hipStream_t stream){
  const float* x  = (const float*)d_in[0];
  const float* Wx = (const float*)d_in[1];
  const float* bx = (const float*)d_in[2];
  const float* Wu = (const float*)d_in[3];
  const float* bu = (const float*)d_in[4];
  const float* W1 = (const float*)d_in[5];
  const float* b1 = (const float*)d_in[6];
  const float* W2 = (const float*)d_in[7];
  const float* b2 = (const float*)d_in[8];
  const float* W3 = (const float*)d_in[9];
  const float* b3 = (const float*)d_in[10];
  float* out = (float*)d_out;

  const int batch   = in_sizes[0] / 25;
  const int nblocks = batch / BM;
  const size_t ws_need = (size_t)(32*64*64*8 + 4096*8) * sizeof(unsigned short); // ~2.1 MB
  const int smem = 5120 + BM*H1S;   // 137216 B

  if (ws_size >= ws_need){
    unsigned short* w2opt = (unsigned short*)d_ws;
    unsigned short* w1opt = w2opt + (size_t)32*64*64*8;
    prep_kernel<<<512, 256, 0, stream>>>(W1, W2, w2opt, w1opt);
    hipFuncSetAttribute(reinterpret_cast<const void*>(mlp_kernel<true>),
                        hipFuncAttributeMaxDynamicSharedMemorySize, smem);
    mlp_kernel<true><<<nblocks, THREADS, smem, stream>>>(
        x, Wx, bx, Wu, bu, W1, b1, W2, b2, W3, b3, w2opt, w1opt, out);
  } else {
    hipFuncSetAttribute(reinterpret_cast<const void*>(mlp_kernel<false>),
                        hipFuncAttributeMaxDynamicSharedMemorySize, smem);
    mlp_kernel<false><<<nblocks, THREADS, smem, stream>>>(
        x, Wx, bx, Wu, bu, W1, b1, W2, b2, W3, b3, nullptr, nullptr, out);
  }
}